// Round 11
// baseline (916.121 us; speedup 1.0000x reference)
//
#include <hip/hip_runtime.h>

#define T_SEQ 512
#define HID 64
#define MB 16             // batch rows per block
#define NTHREADS 1024
// Wave roles: 0-7 = L1 (2 tiles each), 8-11 = L2 (4 tiles each, one shared
// read-set per wave), 12-15 = x-staging only.
// OPERAND-FLIPPED MFMA: A = weights (regs), B = h (LDS). D[gate-unit][batch].
// A1 row: [0,64) h1 (perm U1), [64,71) x (natural), [71,96) zero.  K1=96
// A2 row: [0,64) h2 (perm U2).                                     K2=128
// U1(p) = (p&~7)+((p&7)>>1)+((p&1)<<2)   (L1 packed-pair store)
// U2(p) = (p&~15)+((p&3)<<2)+((p>>2)&3)  (L2 packed-quad store)
// Strides: 104 shorts = 52 dw == 20 mod 32 (20=4*5, 5 odd -> full bank spread,
// 2-way max). R10's A2STR=72 (36 dw == 4 mod 32) was an 8-way conflict bug.
#define A1STR 104
#define A2STR 104

typedef __attribute__((ext_vector_type(8))) short short8;
typedef __attribute__((ext_vector_type(4))) float floatx4;

#define LOG2E 1.4426950408889634f

__device__ __forceinline__ short f2bf_rne(float v) {
  unsigned u = __float_as_uint(v);
  return (short)((u + 0x7FFFu + ((u >> 16) & 1u)) >> 16);
}
__device__ __forceinline__ float rcp_(float x) { return __builtin_amdgcn_rcpf(x); }
__device__ __forceinline__ float exp2_(float x) { return __builtin_amdgcn_exp2f(x); }

// gates pre-scaled: p[0,1,3] by LOG2E, p[2] by 2*LOG2E. rcp-fused forms:
// sig(a)*tanh(y) = (G-1)*rcp((1+A)(G+1)); h = (C-1)*rcp((1+O)(C+1))
__device__ __forceinline__ float gate_h(const floatx4 p, float& c) {
  float A = exp2_(-p[0]);
  float F = exp2_(-p[1]);
  float G = exp2_(p[2]);
  float O = exp2_(-p[3]);
  float ig = (G - 1.f) * rcp_((1.f + A) * (G + 1.f));
  c = rcp_(1.f + F) * c + ig;
  float C = exp2_((2.f * LOG2E) * c);
  return (C - 1.f) * rcp_((1.f + O) * (C + 1.f));
}

__device__ __forceinline__ int U1(int p) {
  return (p & ~7) + ((p & 7) >> 1) + ((p & 1) << 2);
}
__device__ __forceinline__ int U2(int p) {
  return (p & ~15) + ((p & 3) << 2) + ((p >> 2) & 3);
}

// Layer-1 weight at k-slot (K1=96): k<64 pairs h1 position U1(k); 64..70 x
__device__ __forceinline__ short w1elem(int k, int n, float wsc,
                                        const float* __restrict__ Wih0,
                                        const float* __restrict__ Whh0) {
  float v;
  if      (k < 64) { v = Whh0[n*64 + U1(k)]; }
  else if (k < 71) { v = Wih0[n*7 + (k - 64)]; }
  else return (short)0;
  return f2bf_rne(v * wsc);
}
// Layer-2 weight (K2=128): k<64 pairs h1 pos U1(k); 64..127 pairs h2 pos U2(k-64)
__device__ __forceinline__ short w2elem(int k, int n, float wsc,
                                        const float* __restrict__ Wih1,
                                        const float* __restrict__ Whh1) {
  float v;
  if (k < 64) { v = Wih1[n*64 + U1(k)]; }
  else        { v = Whh1[n*64 + U2(k - 64)]; }
  return f2bf_rne(v * wsc);
}

#define MFMA(A, B, C) __builtin_amdgcn_mfma_f32_16x16x32_bf16((A), (B), (C), 0, 0, 0)

#define PACK2(ha, hb)                                                        \
  ((unsigned)(unsigned short)f2bf_rne(ha) |                                  \
   ((unsigned)(unsigned short)f2bf_rne(hb) << 16))

__global__ __launch_bounds__(NTHREADS, 4) void lstm_fused(
    const float* __restrict__ x,
    const float* __restrict__ Wih0, const float* __restrict__ Whh0,
    const float* __restrict__ bih0, const float* __restrict__ bhh0,
    const float* __restrict__ Wih1, const float* __restrict__ Whh1,
    const float* __restrict__ bih1, const float* __restrict__ bhh1,
    const float* __restrict__ Wfc,  const float* __restrict__ bfc,
    float* __restrict__ out)
{
  __shared__ __align__(16) short A1[2][MB][A1STR];
  __shared__ __align__(16) short A2[2][MB][A2STR];
  __shared__ float h2f[MB][HID + 4];

  const int tid  = threadIdx.x;
  const int lane = tid & 63;
  const int wave = tid >> 6;           // 0..15
  const int l15  = lane & 15;          // batch column
  const int quad = lane >> 4;
  const int quad8= quad * 8;
  const int g4   = l15 & 3;
  const int b0   = blockIdx.x * MB;
  const bool isL1 = (wave < 8);
  const bool isL2 = (wave >= 8) && (wave < 12);
  const float wsc = (g4 == 2) ? 2.f * LOG2E : LOG2E;

  // ---- zero both staging buffers (h(-1) = 0, x pad = 0) ----
  for (int i = tid; i < 2*MB*A1STR/2; i += NTHREADS) ((unsigned*)A1)[i] = 0u;
  for (int i = tid; i < 2*MB*A2STR/2; i += NTHREADS) ((unsigned*)A2)[i] = 0u;

  // ================= role-specific setup =================
  // --- L1 (waves 0-7): 2 tiles; units u0 = wl*8+quad, u1 = u0+4 ---
  const int wl   = wave & 7;
  const int u0   = wl*8 + quad;
  const int u1   = u0 + 4;
  const int hpos = wl*8 + 2*quad;              // L1 packed-pair store position
  // --- L2 (waves 8-11): 4 tiles; units u_t = wl2*16 + 4t + quad ---
  const int wl2  = wave - 8;
  const int hbase2 = wl2*16 + quad*4;          // L2 packed-quad store position
  // --- x-staging (waves 12-15) ---
  const int xid  = tid - 768;                  // 0..255
  const bool xact = (wave >= 12) && (xid < MB*7);
  const int xrow = xid / 7, xd = xid - xrow * 7;
  const float* xbase = x + ((size_t)(b0 + (xrow & 15)) * T_SEQ) * 7 + xd;
  float xcur = 0.f;
  if (xact) {
    A1[0][xrow][64 + xd] = f2bf_rne(xbase[0]);
    xcur = xbase[7];
  }

  // ---- weights + biases in registers ----
  short8 W1f[3][2];      // L1: [kstep][tile]
  short8 W2f[4][4];      // L2: [kstep][tile]
  floatx4 bA, bB;        // L1 biases
  floatx4 b2[4];         // L2 biases
  if (isL1) {
    const int n0 = g4*64 + (wl*8 + (l15 >> 2));
    const int n1 = n0 + 4;
    #pragma unroll
    for (int ks = 0; ks < 3; ++ks) {
      short8 fa, fb;
      #pragma unroll
      for (int jj = 0; jj < 8; ++jj) {
        fa[jj] = w1elem(ks*32 + quad8 + jj, n0, wsc, Wih0, Whh0);
        fb[jj] = w1elem(ks*32 + quad8 + jj, n1, wsc, Wih0, Whh0);
      }
      W1f[ks][0] = fa; W1f[ks][1] = fb;
    }
    #pragma unroll
    for (int g = 0; g < 4; ++g) {
      float ws = (g == 2) ? 2.f * LOG2E : LOG2E;
      bA[g] = (bih0[g*64 + u0] + bhh0[g*64 + u0]) * ws;
      bB[g] = (bih0[g*64 + u1] + bhh0[g*64 + u1]) * ws;
    }
  } else if (isL2) {
    #pragma unroll
    for (int t = 0; t < 4; ++t) {
      const int nt = g4*64 + (wl2*16 + 4*t + (l15 >> 2));
      #pragma unroll
      for (int ks = 0; ks < 4; ++ks) {
        short8 f;
        #pragma unroll
        for (int jj = 0; jj < 8; ++jj)
          f[jj] = w2elem(ks*32 + quad8 + jj, nt, wsc, Wih1, Whh1);
        W2f[ks][t] = f;
      }
      const int ut = wl2*16 + 4*t + quad;
      #pragma unroll
      for (int g = 0; g < 4; ++g) {
        float ws = (g == 2) ? 2.f * LOG2E : LOG2E;
        b2[t][g] = (bih1[g*64 + ut] + bhh1[g*64 + ut]) * ws;
      }
    }
  }
  __syncthreads();

  float c1a = 0.f, c1b = 0.f;     // L1 c-states
  float c2s[4] = {0.f, 0.f, 0.f, 0.f};  // L2 c-states

#define STEP_X(NXT, XT)                                                      \
    if (xact) {                                                              \
      A1[NXT][xrow][64 + xd] = f2bf_rne(xcur);                               \
      xcur = xbase[7 * (XT)];                                                \
    }

#define L1_BODY(CUR, NXT)                                                    \
    { short8 hf0 = *(const short8*)&A1[CUR][l15][     quad8];                \
      short8 hf1 = *(const short8*)&A1[CUR][l15][32 + quad8];                \
      short8 hfx = *(const short8*)&A1[CUR][l15][64 + quad8];                \
      floatx4 pa = bA, pb = bB;                                              \
      pa = MFMA(W1f[0][0], hf0, pa);  pb = MFMA(W1f[0][1], hf0, pb);         \
      pa = MFMA(W1f[1][0], hf1, pa);  pb = MFMA(W1f[1][1], hf1, pb);         \
      pa = MFMA(W1f[2][0], hfx, pa);  pb = MFMA(W1f[2][1], hfx, pb);         \
      float ha = gate_h(pa, c1a);                                            \
      float hb = gate_h(pb, c1b);                                            \
      *(unsigned*)&A1[NXT][l15][hpos] = PACK2(ha, hb); }

#define L2_BODY(CUR, NXT)                                                    \
    { short8 hf0 = *(const short8*)&A1[CUR][l15][     quad8];                \
      short8 hf1 = *(const short8*)&A1[CUR][l15][32 + quad8];                \
      short8 h20 = *(const short8*)&A2[CUR][l15][     quad8];                \
      short8 h21 = *(const short8*)&A2[CUR][l15][32 + quad8];                \
      floatx4 p0 = b2[0], p1 = b2[1], p2v = b2[2], p3 = b2[3];               \
      p0 = MFMA(W2f[0][0], hf0, p0);  p1 = MFMA(W2f[0][1], hf0, p1);         \
      p2v= MFMA(W2f[0][2], hf0, p2v); p3 = MFMA(W2f[0][3], hf0, p3);         \
      p0 = MFMA(W2f[1][0], hf1, p0);  p1 = MFMA(W2f[1][1], hf1, p1);         \
      p2v= MFMA(W2f[1][2], hf1, p2v); p3 = MFMA(W2f[1][3], hf1, p3);         \
      p0 = MFMA(W2f[2][0], h20, p0);  p1 = MFMA(W2f[2][1], h20, p1);         \
      p2v= MFMA(W2f[2][2], h20, p2v); p3 = MFMA(W2f[2][3], h20, p3);         \
      p0 = MFMA(W2f[3][0], h21, p0);  p1 = MFMA(W2f[3][1], h21, p1);         \
      p2v= MFMA(W2f[3][2], h21, p2v); p3 = MFMA(W2f[3][3], h21, p3);         \
      float h0 = gate_h(p0, c2s[0]);                                         \
      float h1v= gate_h(p1, c2s[1]);                                         \
      float h2v= gate_h(p2v, c2s[2]);                                        \
      float h3 = gate_h(p3, c2s[3]);                                         \
      uint2 pk; pk.x = PACK2(h0, h1v); pk.y = PACK2(h2v, h3);                \
      *(uint2*)&A2[NXT][l15][hbase2] = pk; }

#define STEP_FULL(CUR, NXT, IT)                                              \
  {                                                                          \
    if (isL1) { L1_BODY(CUR, NXT) }                                          \
    else if (isL2) { L2_BODY(CUR, NXT) }                                     \
    else { int xt_ = (IT) + 2; if (xt_ > T_SEQ - 1) xt_ = T_SEQ - 1;         \
           STEP_X(NXT, xt_) }                                                \
    __syncthreads();                                                         \
  }

  // ---- it = 0: L1 + x only (A2[1] keeps zeros = h2(-1)) ----
  {
    if (isL1) { L1_BODY(0, 1) }
    else if (!isL2) { STEP_X(1, 2) }
    __syncthreads();
  }

  // ---- main: it = 1..510, two steps per trip ----
  #pragma unroll 1
  for (int k = 0; k < 255; ++k) {
    STEP_FULL(1, 0, 2*k + 1)
    STEP_FULL(0, 1, 2*k + 2)
  }
  // ---- it = 511 ----
  STEP_FULL(1, 0, 511)

  // ---- it = 512: L2 only; write final h2 as f32 ----
  {
    if (isL2) {
      short8 hf0 = *(const short8*)&A1[0][l15][     quad8];
      short8 hf1 = *(const short8*)&A1[0][l15][32 + quad8];
      short8 h20 = *(const short8*)&A2[0][l15][     quad8];
      short8 h21 = *(const short8*)&A2[0][l15][32 + quad8];
      floatx4 p0 = b2[0], p1 = b2[1], p2v = b2[2], p3 = b2[3];
      p0 = MFMA(W2f[0][0], hf0, p0);  p1 = MFMA(W2f[0][1], hf0, p1);
      p2v= MFMA(W2f[0][2], hf0, p2v); p3 = MFMA(W2f[0][3], hf0, p3);
      p0 = MFMA(W2f[1][0], hf1, p0);  p1 = MFMA(W2f[1][1], hf1, p1);
      p2v= MFMA(W2f[1][2], hf1, p2v); p3 = MFMA(W2f[1][3], hf1, p3);
      p0 = MFMA(W2f[2][0], h20, p0);  p1 = MFMA(W2f[2][1], h20, p1);
      p2v= MFMA(W2f[2][2], h20, p2v); p3 = MFMA(W2f[2][3], h20, p3);
      p0 = MFMA(W2f[3][0], h21, p0);  p1 = MFMA(W2f[3][1], h21, p1);
      p2v= MFMA(W2f[3][2], h21, p2v); p3 = MFMA(W2f[3][3], h21, p3);
      h2f[l15][wl2*16 +  0 + quad] = gate_h(p0, c2s[0]);
      h2f[l15][wl2*16 +  4 + quad] = gate_h(p1, c2s[1]);
      h2f[l15][wl2*16 +  8 + quad] = gate_h(p2v, c2s[2]);
      h2f[l15][wl2*16 + 12 + quad] = gate_h(p3, c2s[3]);
    }
    __syncthreads();
  }

  // ---- final FC ----
  if (tid < MB * 4) {
    int bbf = tid >> 2, o = tid & 3;
    float acc = bfc[o];
    #pragma unroll 8
    for (int kk = 0; kk < HID; ++kk) acc += h2f[bbf][kk] * Wfc[o*HID + kk];
    out[(size_t)(b0 + bbf) * 4 + o] = acc;
  }
}

extern "C" void kernel_launch(void* const* d_in, const int* in_sizes, int n_in,
                              void* d_out, int out_size, void* d_ws, size_t ws_size,
                              hipStream_t stream) {
  const float* x    = (const float*)d_in[0];
  const float* Wih0 = (const float*)d_in[1];
  const float* Whh0 = (const float*)d_in[2];
  const float* bih0 = (const float*)d_in[3];
  const float* bhh0 = (const float*)d_in[4];
  const float* Wih1 = (const float*)d_in[5];
  const float* Whh1 = (const float*)d_in[6];
  const float* bih1 = (const float*)d_in[7];
  const float* bhh1 = (const float*)d_in[8];
  const float* Wfc  = (const float*)d_in[9];
  const float* bfc  = (const float*)d_in[10];
  (void)d_ws; (void)ws_size; (void)n_in; (void)out_size;

  const int B = in_sizes[0] / (T_SEQ * 7);   // 4096
  dim3 grid(B / MB);
  lstm_fused<<<grid, NTHREADS, 0, stream>>>(x, Wih0, Whh0, bih0, bhh0,
                                            Wih1, Whh1, bih1, bhh1, Wfc, bfc,
                                            (float*)d_out);
}

// Round 12
// 438.461 us; speedup vs baseline: 2.0894x; 2.0894x over previous
//
#include <hip/hip_runtime.h>

#define T_SEQ 512
#define HID 64
#define MB 16             // batch rows per block
#define NTHREADS 1024     // 16 waves: 0-7 layer1 (2 tiles), 8-15 layer2 (2 tiles)
// OPERAND-FLIPPED MFMA: A = weights (regs), B = h (LDS). D[gate-unit][batch].
// LAYER-SPLIT: L1 waves read {h1 x2, x} = 3 b128; L2 waves read {h1 x2, h2 x2} = 4.
// Both tiles of a wave share B-fragments -> 56 b128/CU-iter.
// UNIT PERMUTATION: LDS position p holds unit U(p) = (p&~7)+((p&7)>>1)+((p&1)<<2)
// -> thread (wl,quad) owns units at adjacent positions: single packed b32 h-store.
// Strides: BOTH 104 shorts = 52 dw == 20 mod 32 (20=4*5, 5 odd -> full bank
// spread, 2-way max). R10's A2STR=72 (36 dw == 4 mod 32) was an 8-way bug.
// R11 lesson: 4-tile waves (64 VGPR of weights) spill -> 2 tiles/wave max.
#define A1STR 104
#define A2STR 104

typedef __attribute__((ext_vector_type(8))) short short8;
typedef __attribute__((ext_vector_type(4))) float floatx4;

#define LOG2E 1.4426950408889634f

__device__ __forceinline__ short f2bf_rne(float v) {
  unsigned u = __float_as_uint(v);
  return (short)((u + 0x7FFFu + ((u >> 16) & 1u)) >> 16);
}
__device__ __forceinline__ float rcp_(float x) { return __builtin_amdgcn_rcpf(x); }
__device__ __forceinline__ float exp2_(float x) { return __builtin_amdgcn_exp2f(x); }

// gates pre-scaled: p[0,1,3] by LOG2E, p[2] by 2*LOG2E. rcp-fused (R11-validated):
// sig(i)*tanh(g) = (G-1)*rcp((1+A)(G+1)); h = (C-1)*rcp((1+O)(C+1))
__device__ __forceinline__ float gate_h(const floatx4 p, float& c) {
  float A = exp2_(-p[0]);
  float F = exp2_(-p[1]);
  float G = exp2_(p[2]);
  float O = exp2_(-p[3]);
  float ig = (G - 1.f) * rcp_((1.f + A) * (G + 1.f));
  c = rcp_(1.f + F) * c + ig;
  float C = exp2_((2.f * LOG2E) * c);
  return (C - 1.f) * rcp_((1.f + O) * (C + 1.f));
}

// unit stored at LDS h-position p
__device__ __forceinline__ int uofp(int p) {
  return (p & ~7) + ((p & 7) >> 1) + ((p & 1) << 2);
}

// Layer-1 weight at A-frag k-slot (K1=96): k<64 pairs h1 positions, 64..70 x
__device__ __forceinline__ short w1elem(int k, int n, float wsc,
                                        const float* __restrict__ Wih0,
                                        const float* __restrict__ Whh0) {
  float v;
  if      (k < 64) { v = Whh0[n*64 + uofp(k)]; }
  else if (k < 71) { v = Wih0[n*7 + (k - 64)]; }
  else return (short)0;
  return f2bf_rne(v * wsc);
}
// Layer-2 weight (K2=128): k<64 pairs h1 positions, 64..127 pairs h2 positions
__device__ __forceinline__ short w2elem(int k, int n, float wsc,
                                        const float* __restrict__ Wih1,
                                        const float* __restrict__ Whh1) {
  float v;
  if (k < 64) { v = Wih1[n*64 + uofp(k)]; }
  else        { v = Whh1[n*64 + uofp(k - 64)]; }
  return f2bf_rne(v * wsc);
}

// A = weights (first arg), B = h (second arg)
#define MFMA(A, B, C) __builtin_amdgcn_mfma_f32_16x16x32_bf16((A), (B), (C), 0, 0, 0)

#define PACK2(ha, hb)                                                        \
  ((unsigned)(unsigned short)f2bf_rne(ha) |                                  \
   ((unsigned)(unsigned short)f2bf_rne(hb) << 16))

__global__ __launch_bounds__(NTHREADS, 4) void lstm_fused(
    const float* __restrict__ x,
    const float* __restrict__ Wih0, const float* __restrict__ Whh0,
    const float* __restrict__ bih0, const float* __restrict__ bhh0,
    const float* __restrict__ Wih1, const float* __restrict__ Whh1,
    const float* __restrict__ bih1, const float* __restrict__ bhh1,
    const float* __restrict__ Wfc,  const float* __restrict__ bfc,
    float* __restrict__ out)
{
  __shared__ __align__(16) short A1[2][MB][A1STR];
  __shared__ __align__(16) short A2[2][MB][A2STR];
  __shared__ float h2f[MB][HID + 4];

  const int tid  = threadIdx.x;
  const int lane = tid & 63;
  const int wave = tid >> 6;           // 0..15
  const int wl   = wave & 7;           // index within layer group
  const bool isL1 = wave < 8;
  const int l15  = lane & 15;          // batch column
  const int quad = lane >> 4;
  const int quad8= quad * 8;
  const int g4   = l15 & 3;
  const int b0   = blockIdx.x * MB;
  const int u0   = wl*8 + quad;        // tile-0 owned unit
  const int u1   = u0 + 4;             // tile-1 owned unit
  const int hpos = wl*8 + 2*quad;      // packed h position (shorts, even)
  const int n0   = g4*64 + (wl*8 + (l15 >> 2));   // tile-0 weight row
  const int n1   = n0 + 4;                        // tile-1 weight row
  const float wsc = (g4 == 2) ? 2.f * LOG2E : LOG2E;

  // ---- zero both staging buffers (h(-1) = 0, x pad = 0) ----
  for (int i = tid; i < 2*MB*A1STR/2; i += NTHREADS) ((unsigned*)A1)[i] = 0u;
  for (int i = tid; i < 2*MB*A2STR/2; i += NTHREADS) ((unsigned*)A2)[i] = 0u;

  // ---- biases for owned units (this thread's layer) ----
  const float* bi_ = isL1 ? bih0 : bih1;
  const float* bh_ = isL1 ? bhh0 : bhh1;
  floatx4 bia, bib;
  #pragma unroll
  for (int g = 0; g < 4; ++g) {
    float ws = (g == 2) ? 2.f * LOG2E : LOG2E;
    bia[g] = (bi_[g*64 + u0] + bh_[g*64 + u0]) * ws;
    bib[g] = (bi_[g*64 + u1] + bh_[g*64 + u1]) * ws;
  }

  // ---- x staging: spread across all 8 L1 waves (2 batch rows each) ----
  const int xd   = lane & 31;
  const int xrow = 2*wl + (lane >> 5);
  const bool xact = isL1 && (xd < 7);
  const float* xbase = x + ((size_t)(b0 + xrow) * T_SEQ) * 7 + xd;
  float xcur = 0.f;
  if (xact) {
    A1[0][xrow][64 + xd] = f2bf_rne(xbase[0]);
    xcur = xbase[7];
  }

  // ---- weight A-fragments (per layer group; tiles a/b) ----
  short8 WA[4], WB[4];
  if (isL1) {
    #pragma unroll
    for (int ks = 0; ks < 3; ++ks) {
      short8 fa, fb;
      #pragma unroll
      for (int jj = 0; jj < 8; ++jj) {
        fa[jj] = w1elem(ks*32 + quad8 + jj, n0, wsc, Wih0, Whh0);
        fb[jj] = w1elem(ks*32 + quad8 + jj, n1, wsc, Wih0, Whh0);
      }
      WA[ks] = fa; WB[ks] = fb;
    }
  } else {
    #pragma unroll
    for (int ks = 0; ks < 4; ++ks) {
      short8 fa, fb;
      #pragma unroll
      for (int jj = 0; jj < 8; ++jj) {
        fa[jj] = w2elem(ks*32 + quad8 + jj, n0, wsc, Wih1, Whh1);
        fb[jj] = w2elem(ks*32 + quad8 + jj, n1, wsc, Wih1, Whh1);
      }
      WA[ks] = fa; WB[ks] = fb;
    }
  }
  __syncthreads();

  float ca = 0.f, cb = 0.f;   // c-state for owned (layer, unit) pair

#define STEP_X(NXT, XT)                                                      \
    if (xact) {                                                              \
      A1[NXT][xrow][64 + xd] = f2bf_rne(xcur);                               \
      xcur = xbase[7 * (XT)];                                                \
    }

#define STEP_FULL(CUR, NXT, IT)                                              \
  {                                                                          \
    if (isL1) {                                                              \
      int xt_ = (IT) + 2; if (xt_ > T_SEQ - 1) xt_ = T_SEQ - 1;              \
      STEP_X(NXT, xt_)                                                       \
      short8 hf0 = *(const short8*)&A1[CUR][l15][     quad8];                \
      short8 hf1 = *(const short8*)&A1[CUR][l15][32 + quad8];                \
      short8 hfx = *(const short8*)&A1[CUR][l15][64 + quad8];                \
      floatx4 pa = bia, pb = bib;                                            \
      pa = MFMA(WA[0], hf0, pa);  pb = MFMA(WB[0], hf0, pb);                 \
      pa = MFMA(WA[1], hf1, pa);  pb = MFMA(WB[1], hf1, pb);                 \
      pa = MFMA(WA[2], hfx, pa);  pb = MFMA(WB[2], hfx, pb);                 \
      float ha = gate_h(pa, ca);                                             \
      float hb = gate_h(pb, cb);                                             \
      *(unsigned*)&A1[NXT][l15][hpos] = PACK2(ha, hb);                       \
    } else {                                                                 \
      short8 hf0 = *(const short8*)&A1[CUR][l15][     quad8];                \
      short8 hf1 = *(const short8*)&A1[CUR][l15][32 + quad8];                \
      short8 h20 = *(const short8*)&A2[CUR][l15][     quad8];                \
      short8 h21 = *(const short8*)&A2[CUR][l15][32 + quad8];                \
      floatx4 pa = bia, pb = bib;                                            \
      pa = MFMA(WA[0], hf0, pa);  pb = MFMA(WB[0], hf0, pb);                 \
      pa = MFMA(WA[1], hf1, pa);  pb = MFMA(WB[1], hf1, pb);                 \
      pa = MFMA(WA[2], h20, pa);  pb = MFMA(WB[2], h20, pb);                 \
      pa = MFMA(WA[3], h21, pa);  pb = MFMA(WB[3], h21, pb);                 \
      float ha = gate_h(pa, ca);                                             \
      float hb = gate_h(pb, cb);                                             \
      *(unsigned*)&A2[NXT][l15][hpos] = PACK2(ha, hb);                       \
    }                                                                        \
    __syncthreads();                                                         \
  }

  // ---- it = 0: L1 only (A2[1] keeps zeros = h2(-1)) ----
  {
    if (isL1) {
      STEP_X(1, 2)
      short8 hf0 = *(const short8*)&A1[0][l15][     quad8];
      short8 hf1 = *(const short8*)&A1[0][l15][32 + quad8];
      short8 hfx = *(const short8*)&A1[0][l15][64 + quad8];
      floatx4 pa = bia, pb = bib;
      pa = MFMA(WA[0], hf0, pa);  pb = MFMA(WB[0], hf0, pb);
      pa = MFMA(WA[1], hf1, pa);  pb = MFMA(WB[1], hf1, pb);
      pa = MFMA(WA[2], hfx, pa);  pb = MFMA(WB[2], hfx, pb);
      float ha = gate_h(pa, ca);
      float hb = gate_h(pb, cb);
      *(unsigned*)&A1[1][l15][hpos] = PACK2(ha, hb);
    }
    __syncthreads();
  }

  // ---- main: it = 1..510, two steps per trip ----
  #pragma unroll 1
  for (int k = 0; k < 255; ++k) {
    STEP_FULL(1, 0, 2*k + 1)
    STEP_FULL(0, 1, 2*k + 2)
  }
  // ---- it = 511 ----
  STEP_FULL(1, 0, 511)

  // ---- it = 512: L2 only; write final h2 as f32 (natural unit index) ----
  {
    if (!isL1) {
      short8 hf0 = *(const short8*)&A1[0][l15][     quad8];
      short8 hf1 = *(const short8*)&A1[0][l15][32 + quad8];
      short8 h20 = *(const short8*)&A2[0][l15][     quad8];
      short8 h21 = *(const short8*)&A2[0][l15][32 + quad8];
      floatx4 pa = bia, pb = bib;
      pa = MFMA(WA[0], hf0, pa);  pb = MFMA(WB[0], hf0, pb);
      pa = MFMA(WA[1], hf1, pa);  pb = MFMA(WB[1], hf1, pb);
      pa = MFMA(WA[2], h20, pa);  pb = MFMA(WB[2], h20, pb);
      pa = MFMA(WA[3], h21, pa);  pb = MFMA(WB[3], h21, pb);
      h2f[l15][u0] = gate_h(pa, ca);
      h2f[l15][u1] = gate_h(pb, cb);
    }
    __syncthreads();
  }

  // ---- final FC ----
  if (tid < MB * 4) {
    int bbf = tid >> 2, o = tid & 3;
    float acc = bfc[o];
    #pragma unroll 8
    for (int kk = 0; kk < HID; ++kk) acc += h2f[bbf][kk] * Wfc[o*HID + kk];
    out[(size_t)(b0 + bbf) * 4 + o] = acc;
  }
}

extern "C" void kernel_launch(void* const* d_in, const int* in_sizes, int n_in,
                              void* d_out, int out_size, void* d_ws, size_t ws_size,
                              hipStream_t stream) {
  const float* x    = (const float*)d_in[0];
  const float* Wih0 = (const float*)d_in[1];
  const float* Whh0 = (const float*)d_in[2];
  const float* bih0 = (const float*)d_in[3];
  const float* bhh0 = (const float*)d_in[4];
  const float* Wih1 = (const float*)d_in[5];
  const float* Whh1 = (const float*)d_in[6];
  const float* bih1 = (const float*)d_in[7];
  const float* bhh1 = (const float*)d_in[8];
  const float* Wfc  = (const float*)d_in[9];
  const float* bfc  = (const float*)d_in[10];
  (void)d_ws; (void)ws_size; (void)n_in; (void)out_size;

  const int B = in_sizes[0] / (T_SEQ * 7);   // 4096
  dim3 grid(B / MB);
  lstm_fused<<<grid, NTHREADS, 0, stream>>>(x, Wih0, Whh0, bih0, bhh0,
                                            Wih1, Whh1, bih1, bhh1, Wfc, bfc,
                                            (float*)d_out);
}